// Round 3
// baseline (75.790 us; speedup 1.0000x reference)
//
#include <hip/hip_runtime.h>
#include <cstdint>

#define NB 32
#define NC 512
#define NQ 64
#define ND 512

typedef __attribute__((ext_vector_type(8))) short bf16x8;   // 8 bf16 (4 VGPRs)
typedef __attribute__((ext_vector_type(4))) float f32x4;

__device__ __forceinline__ short f2bf(float f) {   // RNE f32 -> bf16
  union { float f; unsigned u; } v; v.f = f;
  v.u += 0x7fffu + ((v.u >> 16) & 1u);
  return (short)(v.u >> 16);
}

// ===================== kA: S = (ctx*w_m)@q^T (+s_q), softmax, write P + m_ws =====================
// P (bf16 [c][64q]) is stashed in G's part-3 region (floats 1536..1567 of each row);
// kB consumes it before overwriting part 3.
#define PITCH 72
#define CM_OFF 0       // [64][72] ctx*w_m bf16, [c][d]
#define QQ_OFF 4608    // [64][72] query bf16, [q][d]
#define SCS_F 4608     // float idx into smf: s_c[64]
#define SQS_F 4672     // s_q[64]
#define KA_SHORTS 9472

__global__ __launch_bounds__(256) void kA(
    const float* __restrict__ ctx, const float* __restrict__ qry,
    const float* __restrict__ W, float* __restrict__ G, float* __restrict__ m_ws)
{
  __shared__ __align__(16) short sm[KA_SHORTS];
  float* smf = (float*)sm;

  const int t    = threadIdx.x;
  const int lane = t & 63;
  const int w    = t >> 6;        // wave owns c-rows w*16..+15
  const int ln15 = lane & 15;
  const int g    = lane >> 4;
  const int b    = blockIdx.x >> 3;
  const int c0   = (blockIdx.x & 7) * 64;

  const int srow = t >> 4;        // loader: 16 lanes per row-segment
  const int scol = (t & 15) * 4;

  f32x4 acc[4] = {};
  float scp[4] = {0,0,0,0}, sqp[4] = {0,0,0,0};

  for (int kc = 0; kc < 8; ++kc) {
    const int d0 = kc * 64;
    const float4 wc = *(const float4*)(W + d0 + scol);
    const float4 wq = *(const float4*)(W + ND + d0 + scol);
    const float4 wm = *(const float4*)(W + 2*ND + d0 + scol);
    __syncthreads();
    #pragma unroll
    for (int k4 = 0; k4 < 4; ++k4) {
      const int r = k4*16 + srow;
      const float4 cv = *(const float4*)(ctx + ((size_t)(b*NC + c0 + r))*ND + d0 + scol);
      const float4 qv = *(const float4*)(qry + ((size_t)(b*NQ + r))*ND + d0 + scol);
      scp[k4] += cv.x*wc.x + cv.y*wc.y + cv.z*wc.z + cv.w*wc.w;
      sqp[k4] += qv.x*wq.x + qv.y*wq.y + qv.z*wq.z + qv.w*wq.w;
      short4 cs; cs.x = f2bf(cv.x*wm.x); cs.y = f2bf(cv.y*wm.y);
                 cs.z = f2bf(cv.z*wm.z); cs.w = f2bf(cv.w*wm.w);
      short4 qs; qs.x = f2bf(qv.x); qs.y = f2bf(qv.y);
                 qs.z = f2bf(qv.z); qs.w = f2bf(qv.w);
      *(short4*)&sm[CM_OFF + r*PITCH + scol] = cs;
      *(short4*)&sm[QQ_OFF + r*PITCH + scol] = qs;
    }
    __syncthreads();
    #pragma unroll
    for (int kk = 0; kk < 2; ++kk) {
      const bf16x8 a = *(const bf16x8*)&sm[CM_OFF + (w*16 + ln15)*PITCH + kk*32 + g*8];
      #pragma unroll
      for (int n = 0; n < 4; ++n) {
        const bf16x8 bq = *(const bf16x8*)&sm[QQ_OFF + (n*16 + ln15)*PITCH + kk*32 + g*8];
        acc[n] = __builtin_amdgcn_mfma_f32_16x16x32_bf16(a, bq, acc[n], 0, 0, 0);
      }
    }
  }

  #pragma unroll
  for (int k4 = 0; k4 < 4; ++k4) {
    float v = scp[k4], u = sqp[k4];
    v += __shfl_xor(v, 1, 16); v += __shfl_xor(v, 2, 16);
    v += __shfl_xor(v, 4, 16); v += __shfl_xor(v, 8, 16);
    u += __shfl_xor(u, 1, 16); u += __shfl_xor(u, 2, 16);
    u += __shfl_xor(u, 4, 16); u += __shfl_xor(u, 8, 16);
    if (ln15 == 0) { smf[SCS_F + k4*16 + srow] = v; smf[SQS_F + k4*16 + srow] = u; }
  }
  __syncthreads();

  // softmax over q; s_c cancels in softmax, only added to the stored rowmax
  #pragma unroll
  for (int reg = 0; reg < 4; ++reg) {
    const int rloc = w*16 + g*4 + reg;   // local c (C/D row mapping)
    float sv[4];
    #pragma unroll
    for (int n = 0; n < 4; ++n) sv[n] = acc[n][reg] + smf[SQS_F + ln15 + 16*n];
    float mx = fmaxf(fmaxf(sv[0], sv[1]), fmaxf(sv[2], sv[3]));
    mx = fmaxf(mx, __shfl_xor(mx, 1, 16));
    mx = fmaxf(mx, __shfl_xor(mx, 2, 16));
    mx = fmaxf(mx, __shfl_xor(mx, 4, 16));
    mx = fmaxf(mx, __shfl_xor(mx, 8, 16));
    float s = 0.f;
    #pragma unroll
    for (int n = 0; n < 4; ++n) { sv[n] = __expf(sv[n] - mx); s += sv[n]; }
    s += __shfl_xor(s, 1, 16); s += __shfl_xor(s, 2, 16);
    s += __shfl_xor(s, 4, 16); s += __shfl_xor(s, 8, 16);
    const float inv = 1.0f / s;
    if (ln15 == 0) m_ws[b*NC + c0 + rloc] = mx + smf[SCS_F + rloc];
    short* pg = (short*)(G + ((size_t)(b*NC + c0 + rloc))*2048 + 1536);
    #pragma unroll
    for (int n = 0; n < 4; ++n) pg[ln15 + 16*n] = f2bf(sv[n] * inv);
  }
}

// ===================== k2: b = softmax_c(m); attended_context =====================
__global__ __launch_bounds__(256) void k2_partial(
    const float* __restrict__ ctx, const float* __restrict__ m_ws, float* __restrict__ pc)
{
  const int t  = threadIdx.x;
  const int b  = blockIdx.x >> 4;
  const int ch = blockIdx.x & 15;
  __shared__ float r8[8];
  __shared__ float wts[32];

  const float v0 = m_ws[b*NC + t];
  const float v1 = m_ws[b*NC + 256 + t];
  float mx = fmaxf(v0, v1);
  #pragma unroll
  for (int o = 32; o; o >>= 1) mx = fmaxf(mx, __shfl_xor(mx, o, 64));
  if ((t & 63) == 0) r8[t >> 6] = mx;
  __syncthreads();
  mx = fmaxf(fmaxf(r8[0], r8[1]), fmaxf(r8[2], r8[3]));
  float e = __expf(v0 - mx) + __expf(v1 - mx);
  #pragma unroll
  for (int o = 32; o; o >>= 1) e += __shfl_xor(e, o, 64);
  if ((t & 63) == 0) r8[4 + (t >> 6)] = e;
  __syncthreads();
  const float denom = r8[4] + r8[5] + r8[6] + r8[7];
  if (t < 32) wts[t] = __expf(m_ws[b*NC + ch*32 + t] - mx) / denom;
  __syncthreads();

  float s0 = 0.f, s1 = 0.f;
  const float* base = ctx + ((size_t)(b*NC + ch*32))*ND;
  for (int c = 0; c < 32; ++c) {
    const float w = wts[c];
    s0 += w * base[(size_t)c*ND + t];
    s1 += w * base[(size_t)c*ND + t + 256];
  }
  pc[((size_t)(b*16 + ch))*ND + t]       = s0;
  pc[((size_t)(b*16 + ch))*ND + t + 256] = s1;
}

__global__ __launch_bounds__(512) void k2_reduce(
    const float* __restrict__ pc, float* __restrict__ ac)
{
  const int b = blockIdx.x;
  const int d = threadIdx.x;
  float s = 0.f;
  #pragma unroll
  for (int ch = 0; ch < 16; ++ch) s += pc[((size_t)(b*16 + ch))*ND + d];
  ac[b*ND + d] = s;
}

// ===================== kB: aq = P@query + stream ALL FOUR G parts =====================
#define QT_PITCH 72
#define KB_QT_SHORTS 4608     // qT [64 d][72 q] bf16, XOR-swizzled
#define AQP 68
__device__ __forceinline__ int qsw(int dd) {  // q-block swizzle for row dd
  return (((dd & 7) ^ ((dd >> 3) & 7)) * 8);
}

__global__ __launch_bounds__(256) void kB(
    const float* __restrict__ ctx, const float* __restrict__ qry,
    const float* __restrict__ ac, float* __restrict__ G)
{
  __shared__ __align__(16) short qt[KB_QT_SHORTS];
  __shared__ __align__(16) float aqf[32*AQP];

  const int t    = threadIdx.x;
  const int lane = t & 63;
  const int w    = t >> 6;
  const int ln15 = lane & 15;
  const int g    = lane >> 4;
  const int cg   = w & 1;         // c half (16 rows)
  const int dh   = (w >> 1) & 1;  // d half (32 cols) within 64-chunk
  const int b    = blockIdx.x >> 4;
  const int c0   = (blockIdx.x & 15) * 32;

  // loader mapping for qT staging
  const int lq  = t >> 2;         // q row 0..63
  const int ld0 = (t & 3) * 16;   // d sub-block
  // streaming mapping
  const int srow = t >> 4;
  const int scol = (t & 15) * 4;

  // P fragments (A-operand) from G part-3 stash — loaded once, consumed before overwrite
  bf16x8 pa[2];
  {
    const short* ps = (const short*)(G + ((size_t)(b*NC + c0 + cg*16 + ln15))*2048 + 1536);
    pa[0] = *(const bf16x8*)(ps + g*8);
    pa[1] = *(const bf16x8*)(ps + 32 + g*8);
  }

  for (int dc = 0; dc < 8; ++dc) {
    const int d0 = dc * 64;
    // stage query^T for this d-chunk
    const float* qrow = qry + ((size_t)(b*NQ + lq))*ND + d0 + ld0;
    #pragma unroll
    for (int v = 0; v < 4; ++v) {
      const float4 qv = *(const float4*)(qrow + v*4);
      const int dd = ld0 + v*4;
      qt[(dd+0)*QT_PITCH + (lq ^ qsw(dd+0))] = f2bf(qv.x);
      qt[(dd+1)*QT_PITCH + (lq ^ qsw(dd+1))] = f2bf(qv.y);
      qt[(dd+2)*QT_PITCH + (lq ^ qsw(dd+2))] = f2bf(qv.z);
      qt[(dd+3)*QT_PITCH + (lq ^ qsw(dd+3))] = f2bf(qv.w);
    }
    __syncthreads();

    f32x4 acc2[2] = {};
    #pragma unroll
    for (int kk = 0; kk < 2; ++kk) {
      #pragma unroll
      for (int n = 0; n < 2; ++n) {
        const int dd = dh*32 + n*16 + ln15;
        const bf16x8 bq = *(const bf16x8*)&qt[dd*QT_PITCH + ((kk*32 + g*8) ^ qsw(dd))];
        acc2[n] = __builtin_amdgcn_mfma_f32_16x16x32_bf16(pa[kk], bq, acc2[n], 0, 0, 0);
      }
    }
    #pragma unroll
    for (int n = 0; n < 2; ++n)
      #pragma unroll
      for (int reg = 0; reg < 4; ++reg)
        aqf[(cg*16 + g*4 + reg)*AQP + dh*32 + n*16 + ln15] = acc2[n][reg];
    __syncthreads();

    const float4 acv = *(const float4*)(ac + b*ND + d0 + scol);
    #pragma unroll
    for (int k4 = 0; k4 < 2; ++k4) {
      const int r = k4*16 + srow;
      const float4 aq4 = *(const float4*)&aqf[r*AQP + scol];
      const float4 cv  = *(const float4*)(ctx + ((size_t)(b*NC + c0 + r))*ND + d0 + scol);
      float* gp = G + ((size_t)(b*NC + c0 + r))*2048 + d0 + scol;
      *(float4*)(gp)        = cv;                                           // part 0
      *(float4*)(gp + 512)  = aq4;                                          // part 1
      *(float4*)(gp + 1024) = make_float4(cv.x*aq4.x, cv.y*aq4.y,
                                          cv.z*aq4.z, cv.w*aq4.w);          // part 2
      *(float4*)(gp + 1536) = make_float4(cv.x*acv.x, cv.y*acv.y,
                                          cv.z*acv.z, cv.w*acv.w);          // part 3
    }
    __syncthreads();   // aqf/qt reuse next chunk
  }
}

extern "C" void kernel_launch(void* const* d_in, const int* in_sizes, int n_in,
                              void* d_out, int out_size, void* d_ws, size_t ws_size,
                              hipStream_t stream)
{
  const float* ctx = (const float*)d_in[0];
  const float* qry = (const float*)d_in[1];
  const float* W   = (const float*)d_in[2];
  float* G = (float*)d_out;

  float* m_ws = (float*)d_ws;            // [32][512]
  float* pc   = m_ws + NB*NC;            // [32][16][512]
  float* ac   = pc + (size_t)NB*16*ND;   // [32][512]

  kA        <<<dim3(NB*8),  dim3(256), 0, stream>>>(ctx, qry, W, G, m_ws);
  k2_partial<<<dim3(NB*16), dim3(256), 0, stream>>>(ctx, m_ws, pc);
  k2_reduce <<<dim3(NB),    dim3(512), 0, stream>>>(pc, ac);
  kB        <<<dim3(NB*16), dim3(256), 0, stream>>>(ctx, qry, ac, G);
}